// Round 7
// baseline (424.519 us; speedup 1.0000x reference)
//
#include <hip/hip_runtime.h>

#define EPS 1e-6f

constexpr int C    = 128;
constexpr int HW   = 65536;    // 256*256
constexpr int TILE = 64;       // pixels per block
constexpr int NT   = 256;      // 4 waves

typedef __attribute__((ext_vector_type(8))) short bf16x8;
typedef __attribute__((ext_vector_type(4))) float f32x4;

__device__ __forceinline__ unsigned short f2bf(float f) {   // RNE
    unsigned u = __float_as_uint(f);
    u += 0x7fff + ((u >> 16) & 1);
    return (unsigned short)(u >> 16);
}
__device__ __forceinline__ float bf2f(unsigned short u) {
    return __uint_as_float(((unsigned)u) << 16);
}
__device__ __forceinline__ unsigned pack2(float lo, float hi) {
    return (unsigned)f2bf(lo) | ((unsigned)f2bf(hi) << 16);
}

__global__ __launch_bounds__(NT, 8) void spnorm_kernel(
    const float* __restrict__ x, const float* __restrict__ W,
    const float* __restrict__ bias, float* __restrict__ out)
{
    // bufT[p][c]: normalized bf16, transposed, XOR-swizzled (byte ^= (p&15)<<4)
    __shared__ unsigned short bufT[TILE * C];              // 16 KB
    __shared__ float2 red[4][TILE];                        // 2 KB (s1, s2)
    __shared__ float u_s[TILE], se_s[TILE];                // 0.5 KB

    const int tid = threadIdx.x;
    const int l   = tid & 63;
    const int wv  = tid >> 6;                              // wave == channel-group q
    const int batch = blockIdx.x >> 10;                    // 1024 blocks per image
    const int hw0   = (blockIdx.x & 1023) * TILE;
    const int base  = batch * (C * HW) + hw0;

    const int p = l;                                       // pixel within tile
    const int q = wv;                                      // channel group (32 ch)

    // ---- Phase 1: x straight into registers, channel-strided, coalesced across p ----
    float v[32];
    {
        const float* xp = x + base + q * 32 * HW + p;
        #pragma unroll
        for (int i = 0; i < 32; ++i)
            v[i] = xp[i * HW];
    }

    // ---- Phase 2: partial sums -> LDS ----
    {
        float s1 = 0.f, s2 = 0.f;
        #pragma unroll
        for (int i = 0; i < 32; ++i) {
            s1 += v[i];
            s2 = fmaf(v[i], v[i], s2);
        }
        red[q][p] = make_float2(s1, s2);
    }
    __syncthreads();

    // ---- Phase 3: every thread finalizes, normalizes its 32 regs, writes bufT ----
    {
        float2 r0 = red[0][p], r1 = red[1][p], r2 = red[2][p], r3 = red[3][p];
        float s1 = r0.x + r1.x + r2.x + r3.x;
        float s2 = r0.y + r1.y + r2.y + r3.y;
        float u   = s1 * (1.0f / 128.0f);
        float var = fmaxf((s2 - s1 * u) * (1.0f / 127.0f), 0.0f);
        float se  = sqrtf(var) + EPS;
        float iv  = 1.0f / se;
        if (q == 0) {                      // wave-uniform branch
            u_s[p]  = u;
            se_s[p] = se;
        }
        char* tb = (char*)bufT;
        const int rowoff = p * 256;        // 128 ushort per pixel row
        const int swz    = (p & 15) << 4;
        #pragma unroll
        for (int o8 = 0; o8 < 4; ++o8) {
            float n0 = (v[o8 * 8 + 0] - u) * iv;
            float n1 = (v[o8 * 8 + 1] - u) * iv;
            float n2 = (v[o8 * 8 + 2] - u) * iv;
            float n3 = (v[o8 * 8 + 3] - u) * iv;
            float n4 = (v[o8 * 8 + 4] - u) * iv;
            float n5 = (v[o8 * 8 + 5] - u) * iv;
            float n6 = (v[o8 * 8 + 6] - u) * iv;
            float n7 = (v[o8 * 8 + 7] - u) * iv;
            uint4 d;
            d.x = pack2(n0, n1);
            d.y = pack2(n2, n3);
            d.z = pack2(n4, n5);
            d.w = pack2(n6, n7);
            int byte = (rowoff + (q * 4 + o8) * 16) ^ swz;
            *reinterpret_cast<uint4*>(tb + byte) = d;
        }
    }

    // ---- A-fragments: W (fp32 -> bf16); loaded here so v[] is dead first (VGPR cap 64).
    //      Wave wv owns 32 output channels: two 16-row fragment sets.
    const int odr = (l >> 4) << 2;
    bf16x8 afrag[2][4];
    f32x4 binit[2];
    #pragma unroll
    for (int ob = 0; ob < 2; ++ob) {
        const int arow = (wv << 5) + (ob << 4) + (l & 15);
        const int acol0 = (l >> 4) << 3;
        #pragma unroll
        for (int kk = 0; kk < 4; ++kk) {
            const float* wp = W + arow * C + kk * 32 + acol0;
            float4 wa = *reinterpret_cast<const float4*>(wp);
            float4 wb = *reinterpret_cast<const float4*>(wp + 4);
            bf16x8 f;
            f[0] = (short)f2bf(wa.x); f[1] = (short)f2bf(wa.y);
            f[2] = (short)f2bf(wa.z); f[3] = (short)f2bf(wa.w);
            f[4] = (short)f2bf(wb.x); f[5] = (short)f2bf(wb.y);
            f[6] = (short)f2bf(wb.z); f[7] = (short)f2bf(wb.w);
            afrag[ob][kk] = f;
        }
        const int od = (wv << 5) + (ob << 4) + odr;
        binit[ob] = f32x4{ bias[od], bias[od + 1], bias[od + 2], bias[od + 3] };
    }
    __syncthreads();

    // ---- Phase 4: MFMA conv + epilogue. Wave wv: 32 o x 64 px.
    //      B-fragment shared across the two o-sets (halves LDS reads). ----
    {
        const char* tb = (const char*)bufT;
        const int pcol = l & 15;
        const int koff = (l >> 4) << 4;
        const int swz  = pcol << 4;
        float* outp = out + base;

        #pragma unroll
        for (int pt = 0; pt < 4; ++pt) {
            const int pp     = (pt << 4) + pcol;
            const int rowoff = pp * 256;
            f32x4 acc0 = binit[0];
            f32x4 acc1 = binit[1];
            #pragma unroll
            for (int kk = 0; kk < 4; ++kk) {
                int byte = (rowoff + kk * 64 + koff) ^ swz;
                bf16x8 bfrag = *reinterpret_cast<const bf16x8*>(tb + byte);
                acc0 = __builtin_amdgcn_mfma_f32_16x16x32_bf16(afrag[0][kk], bfrag, acc0, 0, 0, 0);
                acc1 = __builtin_amdgcn_mfma_f32_16x16x32_bf16(afrag[1][kk], bfrag, acc1, 0, 0, 0);
            }
            const float uu = u_s[pp];
            const float se = se_s[pp];

            // epilogue, o-set 0 (static acc use)
            {
                const int od = (wv << 5) + odr;
                int nbyte = (rowoff + od * 2) ^ swz;
                uint2 nn = *reinterpret_cast<const uint2*>(tb + nbyte);
                float x0 = fmaf(bf2f((unsigned short)(nn.x & 0xffffu)), se, uu);
                float x1 = fmaf(bf2f((unsigned short)(nn.x >> 16)),     se, uu);
                float x2 = fmaf(bf2f((unsigned short)(nn.y & 0xffffu)), se, uu);
                float x3 = fmaf(bf2f((unsigned short)(nn.y >> 16)),     se, uu);
                outp[(od + 0) * HW + pp] = x0 * acc0[0];
                outp[(od + 1) * HW + pp] = x1 * acc0[1];
                outp[(od + 2) * HW + pp] = x2 * acc0[2];
                outp[(od + 3) * HW + pp] = x3 * acc0[3];
            }
            // epilogue, o-set 1
            {
                const int od = (wv << 5) + 16 + odr;
                int nbyte = (rowoff + od * 2) ^ swz;
                uint2 nn = *reinterpret_cast<const uint2*>(tb + nbyte);
                float x0 = fmaf(bf2f((unsigned short)(nn.x & 0xffffu)), se, uu);
                float x1 = fmaf(bf2f((unsigned short)(nn.x >> 16)),     se, uu);
                float x2 = fmaf(bf2f((unsigned short)(nn.y & 0xffffu)), se, uu);
                float x3 = fmaf(bf2f((unsigned short)(nn.y >> 16)),     se, uu);
                outp[(od + 0) * HW + pp] = x0 * acc1[0];
                outp[(od + 1) * HW + pp] = x1 * acc1[1];
                outp[(od + 2) * HW + pp] = x2 * acc1[2];
                outp[(od + 3) * HW + pp] = x3 * acc1[3];
            }
        }
    }
}

extern "C" void kernel_launch(void* const* d_in, const int* in_sizes, int n_in,
                              void* d_out, int out_size, void* d_ws, size_t ws_size,
                              hipStream_t stream) {
    const float* x = (const float*)d_in[0];
    const float* W = (const float*)d_in[1];
    const float* b = (const float*)d_in[2];
    float* out     = (float*)d_out;

    const int nblk = 8 * HW / TILE;            // 8192 blocks
    spnorm_kernel<<<nblk, NT, 0, stream>>>(x, W, b, out);
}

// Round 8
// 133.140 us; speedup vs baseline: 3.1885x; 3.1885x over previous
//
#include <hip/hip_runtime.h>

#define EPS 1e-6f

constexpr int C    = 128;
constexpr int HW   = 65536;    // 256*256
constexpr int TILE = 256;      // pixels per block (1 KB per channel per block)
constexpr int NT   = 1024;     // 16 waves

typedef __attribute__((ext_vector_type(8))) short bf16x8;
typedef __attribute__((ext_vector_type(4))) float f32x4;

__device__ __forceinline__ unsigned short f2bf(float f) {   // RNE
    unsigned u = __float_as_uint(f);
    u += 0x7fff + ((u >> 16) & 1);
    return (unsigned short)(u >> 16);
}
__device__ __forceinline__ float bf2f(unsigned short u) {
    return __uint_as_float(((unsigned)u) << 16);
}
__device__ __forceinline__ unsigned pack2(float lo, float hi) {
    return (unsigned)f2bf(lo) | ((unsigned)f2bf(hi) << 16);
}

__global__ __launch_bounds__(NT, 2) void spnorm_kernel(
    const float* __restrict__ x, const float* __restrict__ W,
    const float* __restrict__ bias, float* __restrict__ out)
{
    // bufT[p][c]: normalized bf16, transposed, XOR-swizzled (byte ^= (p&15)<<4)
    __shared__ unsigned short bufT[TILE * C];              // 64 KB
    __shared__ float2 red[4][TILE];                        // 8 KB (s1, s2)
    __shared__ float u_s[TILE], se_s[TILE];                // 2 KB

    const int tid = threadIdx.x;
    const int l   = tid & 63;
    const int wv  = tid >> 6;                              // 0..15
    const int batch = blockIdx.x >> 8;                     // 256 blocks per image
    const int hw0   = (blockIdx.x & 255) * TILE;
    const int base  = batch * (C * HW) + hw0;

    const int p = tid & 255;                               // pixel within tile
    const int q = tid >> 8;                                // channel group (32 ch)

    // ---- Phase 1: x straight into registers, channel-strided, coalesced across p.
    //      Block footprint per channel: 256 px * 4 B = 1 KB contiguous. ----
    float v[32];
    {
        const float* xp = x + base + q * 32 * HW + p;
        #pragma unroll
        for (int i = 0; i < 32; ++i)
            v[i] = xp[i * HW];
    }

    // ---- Phase 2: partial sums -> LDS ----
    {
        float s1 = 0.f, s2 = 0.f;
        #pragma unroll
        for (int i = 0; i < 32; ++i) {
            s1 += v[i];
            s2 = fmaf(v[i], v[i], s2);
        }
        red[q][p] = make_float2(s1, s2);
    }
    __syncthreads();

    // ---- Phase 3: every thread finalizes, normalizes its 32 regs, writes bufT ----
    {
        float2 r0 = red[0][p], r1 = red[1][p], r2 = red[2][p], r3 = red[3][p];
        float s1 = r0.x + r1.x + r2.x + r3.x;
        float s2 = r0.y + r1.y + r2.y + r3.y;
        float u   = s1 * (1.0f / 128.0f);
        float var = fmaxf((s2 - s1 * u) * (1.0f / 127.0f), 0.0f);
        float se  = sqrtf(var) + EPS;
        float iv  = 1.0f / se;
        if (q == 0) {                      // wave-uniform branch (tid < 256)
            u_s[p]  = u;
            se_s[p] = se;
        }
        char* tb = (char*)bufT;
        const int rowoff = p * 256;        // 128 ushort per pixel row
        const int swz    = (p & 15) << 4;
        #pragma unroll
        for (int o8 = 0; o8 < 4; ++o8) {
            float n0 = (v[o8 * 8 + 0] - u) * iv;
            float n1 = (v[o8 * 8 + 1] - u) * iv;
            float n2 = (v[o8 * 8 + 2] - u) * iv;
            float n3 = (v[o8 * 8 + 3] - u) * iv;
            float n4 = (v[o8 * 8 + 4] - u) * iv;
            float n5 = (v[o8 * 8 + 5] - u) * iv;
            float n6 = (v[o8 * 8 + 6] - u) * iv;
            float n7 = (v[o8 * 8 + 7] - u) * iv;
            uint4 d;
            d.x = pack2(n0, n1);
            d.y = pack2(n2, n3);
            d.z = pack2(n4, n5);
            d.w = pack2(n6, n7);
            int byte = (rowoff + (q * 4 + o8) * 16) ^ swz;
            *reinterpret_cast<uint4*>(tb + byte) = d;
        }
    }

    // ---- A-fragments: W (fp32 -> bf16); loaded after v[] is dead (VGPR cap 64).
    //      Wave wv -> o-group wm = wv&7 (16 ch), px-half wn = wv>>3. ----
    const int wm = wv & 7;
    const int wn = wv >> 3;
    const int arow  = (wm << 4) + (l & 15);
    const int acol0 = (l >> 4) << 3;
    bf16x8 afrag[4];
    #pragma unroll
    for (int kk = 0; kk < 4; ++kk) {
        const float* wp = W + arow * C + kk * 32 + acol0;
        float4 wa = *reinterpret_cast<const float4*>(wp);
        float4 wb = *reinterpret_cast<const float4*>(wp + 4);
        bf16x8 f;
        f[0] = (short)f2bf(wa.x); f[1] = (short)f2bf(wa.y);
        f[2] = (short)f2bf(wa.z); f[3] = (short)f2bf(wa.w);
        f[4] = (short)f2bf(wb.x); f[5] = (short)f2bf(wb.y);
        f[6] = (short)f2bf(wb.z); f[7] = (short)f2bf(wb.w);
        afrag[kk] = f;
    }
    const int od = (wm << 4) + ((l >> 4) << 2);
    const f32x4 binit = { bias[od], bias[od + 1], bias[od + 2], bias[od + 3] };
    __syncthreads();

    // ---- Phase 4: MFMA conv + epilogue. Wave wv: 16 o x 128 px (its px-half).
    //      Block writes 1 KB contiguous per channel. ----
    {
        const char* tb = (const char*)bufT;
        const int pcol = l & 15;
        const int koff = (l >> 4) << 4;
        const int swz  = pcol << 4;
        float* outp = out + base;
        #pragma unroll
        for (int pt = 0; pt < 8; ++pt) {
            const int pp     = (wn << 7) + (pt << 4) + pcol;
            const int rowoff = pp * 256;
            f32x4 acc = binit;
            #pragma unroll
            for (int kk = 0; kk < 4; ++kk) {
                int byte = (rowoff + kk * 64 + koff) ^ swz;
                bf16x8 bfrag = *reinterpret_cast<const bf16x8*>(tb + byte);
                acc = __builtin_amdgcn_mfma_f32_16x16x32_bf16(afrag[kk], bfrag, acc, 0, 0, 0);
            }
            const float uu = u_s[pp];
            const float se = se_s[pp];
            int nbyte = (rowoff + od * 2) ^ swz;
            uint2 nn = *reinterpret_cast<const uint2*>(tb + nbyte);
            float x0 = fmaf(bf2f((unsigned short)(nn.x & 0xffffu)), se, uu);
            float x1 = fmaf(bf2f((unsigned short)(nn.x >> 16)),     se, uu);
            float x2 = fmaf(bf2f((unsigned short)(nn.y & 0xffffu)), se, uu);
            float x3 = fmaf(bf2f((unsigned short)(nn.y >> 16)),     se, uu);
            outp[(od + 0) * HW + pp] = x0 * acc[0];
            outp[(od + 1) * HW + pp] = x1 * acc[1];
            outp[(od + 2) * HW + pp] = x2 * acc[2];
            outp[(od + 3) * HW + pp] = x3 * acc[3];
        }
    }
}

extern "C" void kernel_launch(void* const* d_in, const int* in_sizes, int n_in,
                              void* d_out, int out_size, void* d_ws, size_t ws_size,
                              hipStream_t stream) {
    const float* x = (const float*)d_in[0];
    const float* W = (const float*)d_in[1];
    const float* b = (const float*)d_in[2];
    float* out     = (float*)d_out;

    const int nblk = 8 * HW / TILE;            // 2048 blocks
    spnorm_kernel<<<nblk, NT, 0, stream>>>(x, W, b, out);
}